// Round 1
// 1695.909 us; speedup vs baseline: 1.6652x; 1.6652x over previous
//
#include <hip/hip_runtime.h>
#include <hip/hip_bf16.h>
#include <stdint.h>

#define D 128
#define KTOT 384
#define BN_EPS 1e-5f

typedef __attribute__((ext_vector_type(8))) short short8;
typedef __attribute__((ext_vector_type(4))) float floatx4;

__device__ __forceinline__ unsigned short f2bf(float f) {
    __hip_bfloat16 b = __float2bfloat16(f);
    return *reinterpret_cast<unsigned short*>(&b);
}
__device__ __forceinline__ float bf2f(unsigned short u) {
    unsigned int b = ((unsigned int)u) << 16;
    return __uint_as_float(b);
}

// ---------------------------------------------------------------------------
// Weight pre-pass: W [K][N] f32 row-major  ->  WT [N][K] bf16 (k-contiguous)
// ---------------------------------------------------------------------------
__global__ void convert_transpose_kernel(const float* __restrict__ W,
                                         unsigned short* __restrict__ WT,
                                         int K, int N)
{
    int idx = blockIdx.x * 256 + threadIdx.x;
    if (idx >= K * N) return;
    int k = idx / N, n = idx % N;
    WT[(size_t)n * K + k] = f2bf(W[idx]);
}

// ---------------------------------------------------------------------------
// CSR-by-dst build: histogram -> two-level exclusive scan -> bucket fill.
// Replaces all float atomic scatters with gathers.
// ---------------------------------------------------------------------------
__global__ void hist_kernel(const int* __restrict__ dst, int* __restrict__ deg, int E)
{
    int e = blockIdx.x * 256 + threadIdx.x;
    if (e < E) atomicAdd(&deg[dst[e]], 1);
}

__global__ void scan_block_kernel(const int* __restrict__ deg,
                                  int* __restrict__ offs,
                                  int* __restrict__ bsum, int N)
{
    __shared__ int s[256];
    int i = blockIdx.x * 256 + threadIdx.x;
    int v = (i < N) ? deg[i] : 0;
    s[threadIdx.x] = v;
    __syncthreads();
#pragma unroll
    for (int off = 1; off < 256; off <<= 1) {
        int t = (threadIdx.x >= off) ? s[threadIdx.x - off] : 0;
        __syncthreads();
        s[threadIdx.x] += t;
        __syncthreads();
    }
    if (i < N) offs[i] = s[threadIdx.x] - v;   // exclusive within block
    if (threadIdx.x == 255) bsum[blockIdx.x] = s[255];
}

__global__ void scan_bsum_kernel(int* __restrict__ bsum, int B)
{
    // single block of 512; B = ceil(N/256) = 391 for N=100000
    __shared__ int s[512];
    int i = threadIdx.x;
    int v = (i < B) ? bsum[i] : 0;
    s[i] = v;
    __syncthreads();
#pragma unroll
    for (int off = 1; off < 512; off <<= 1) {
        int t = (i >= off) ? s[i - off] : 0;
        __syncthreads();
        s[i] += t;
        __syncthreads();
    }
    if (i < B) bsum[i] = s[i] - v;             // exclusive
}

__global__ void scan_add_cursor_kernel(int* __restrict__ offs,
                                       const int* __restrict__ bsum,
                                       int* __restrict__ cursor, int N)
{
    int i = blockIdx.x * 256 + threadIdx.x;
    if (i < N) {
        int o = offs[i] + bsum[blockIdx.x];
        offs[i] = o;
        cursor[i] = o;
    }
}

__global__ void fill_kernel(const int* __restrict__ src,
                            const int* __restrict__ dst,
                            int* __restrict__ cursor,
                            int* __restrict__ el_src,
                            int* __restrict__ el_e, int E)
{
    int e = blockIdx.x * 256 + threadIdx.x;
    if (e < E) {
        int p = atomicAdd(&cursor[dst[e]], 1);
        el_src[p] = src[e];
        el_e[p] = e;
    }
}

// sum_h[n] = h[n] + sum over incoming edges of h[src[e]]  (pure gather)
__global__ void gather_sum_h_kernel(const float* __restrict__ h,
                                    const int* __restrict__ offs,
                                    const int* __restrict__ el_src,
                                    float* __restrict__ sum_h, int N, int E)
{
    int t = blockIdx.x * 256 + threadIdx.x;
    int n = t >> 5;
    if (n >= N) return;
    int c = (t & 31) * 4;
    float4 acc = *(const float4*)(h + (size_t)n * D + c);
    int p = offs[n];
    int pe = (n + 1 < N) ? offs[n + 1] : E;
    for (; p < pe; ++p) {
        int s = el_src[p];                       // uniform across 32-lane group
        const float4 v = *(const float4*)(h + (size_t)s * D + c);
        acc.x += v.x; acc.y += v.y; acc.z += v.z; acc.w += v.w;
    }
    *(float4*)(sum_h + (size_t)n * D + c) = acc;
}

// sum_e[n] = sum over incoming edges of e_new[e]  (pure gather)
__global__ void gather_sum_e_kernel(const float* __restrict__ e_new,
                                    const int* __restrict__ offs,
                                    const int* __restrict__ el_e,
                                    float* __restrict__ sum_e, int N, int E)
{
    int t = blockIdx.x * 256 + threadIdx.x;
    int n = t >> 5;
    if (n >= N) return;
    int c = (t & 31) * 4;
    float4 acc = {0.f, 0.f, 0.f, 0.f};
    int p = offs[n];
    int pe = (n + 1 < N) ? offs[n + 1] : E;
    for (; p < pe; ++p) {
        int e = el_e[p];
        const float4 v = *(const float4*)(e_new + (size_t)e * D + c);
        acc.x += v.x; acc.y += v.y; acc.z += v.z; acc.w += v.w;
    }
    *(float4*)(sum_e + (size_t)n * D + c) = acc;
}

// graph_id is sorted: per-graph segmented sum via binary search, no atomics.
// sum_hg[g] = sum h_new rows; sum_eg[g] = 0.5 * sum sum_e rows.
__global__ __launch_bounds__(128)
void graph_seg_sum_kernel(const float* __restrict__ h_new,
                          const float* __restrict__ sum_e,
                          const int* __restrict__ gid,
                          float* __restrict__ sum_hg,
                          float* __restrict__ sum_eg, int N)
{
    int g = blockIdx.x;
    int lo = 0, hi = N;
    while (lo < hi) { int m = (lo + hi) >> 1; if (gid[m] < g) lo = m + 1; else hi = m; }
    int s0 = lo;
    hi = N;
    while (lo < hi) { int m = (lo + hi) >> 1; if (gid[m] < g + 1) lo = m + 1; else hi = m; }
    int e0 = lo;
    int c = threadIdx.x;
    float aH = 0.f, aE = 0.f;
    for (int n = s0; n < e0; ++n) {
        aH += h_new[(size_t)n * D + c];
        aE += sum_e[(size_t)n * D + c];
    }
    sum_hg[(size_t)g * D + c] = aH;
    sum_eg[(size_t)g * D + c] = 0.5f * aE;
}

// ---------------------------------------------------------------------------
// GEMM1 (MFMA bf16): z = X @ W1 + b1, X assembled on the fly (concat+gather),
// bf16 z store via LDS-staged coalesced writes, fused BN column stats.
// Tile 128x128, BK=32, 256 threads = 4 waves (2x2), each wave 64x64 via
// 4x4 x mfma_f32_16x16x32_bf16.
// MODE 0: edge  X=[h[src]+h[dst], e, u[gid[src]]]
// MODE 1: atom  X=[sum_h, sum_e, u[gid]]
// MODE 2: glob  X=[sum_hg, sum_eg, u]
// ---------------------------------------------------------------------------
template<int MODE>
__global__ __launch_bounds__(256)
void gemm1_mfma_kernel(const float* __restrict__ P0,
                       const float* __restrict__ P1,
                       const float* __restrict__ P2,
                       const int* __restrict__ src,
                       const int* __restrict__ dst,
                       const int* __restrict__ graph_id,
                       const unsigned short* __restrict__ W1T, // [N=384][K=384] bf16
                       const float* __restrict__ b1,
                       unsigned short* __restrict__ z,          // [M][384] bf16
                       float* __restrict__ stat_sum,
                       float* __restrict__ stat_sq,
                       int M)
{
    __shared__ __align__(16) char smem[37376];
    short (*As)[40] = (short(*)[40])smem;
    short (*Bs)[40] = (short(*)[40])(smem + 10240);
    short (*Zs)[136] = (short(*)[136])smem;
    int* s_i0 = (int*)(smem + 34816);
    int* s_i1 = s_i0 + 128;
    int* s_i2 = s_i1 + 128;
    float* s_sum = (float*)(smem + 36352);
    float* s_sq  = s_sum + 128;

    const int tid = threadIdx.x;
    const int row0 = blockIdx.x * 128;
    const int colblk = blockIdx.y * 128;

    if (tid < 128) {
        int r = row0 + tid;
        bool v = r < M;
        if (MODE == 0) {
            int s = v ? src[r] : 0;
            int d = v ? dst[r] : 0;
            s_i0[tid] = s; s_i1[tid] = d;
            s_i2[tid] = v ? graph_id[s] : 0;
        } else if (MODE == 1) {
            s_i2[tid] = v ? graph_id[r] : 0;
        }
        s_sum[tid] = 0.f; s_sq[tid] = 0.f;
    }
    __syncthreads();

    const int lane = tid & 63;
    const int wave = tid >> 6;
    const int wm = wave >> 1, wn = wave & 1;
    const int txl = lane & 15;
    const int quad = lane >> 4;
    const int kofs = quad * 8;

    const int r2 = tid >> 1;            // 0..127: A row / B col
    const int khalf = (tid & 1) * 16;   // 0 or 16

    floatx4 acc[4][4] = {};

    for (int kt = 0; kt < KTOT; kt += 32) {
        // ---- stage A: 16 f32 gathered -> bf16 -> LDS ----
        {
            int gk = kt + khalf;
            float v[16];
            int grow = row0 + r2;
            if (grow < M) {
                const float4* q0; const float4* q1 = nullptr;
                if (MODE == 0) {
                    if (gk < 128) {
                        q0 = (const float4*)(P0 + (size_t)s_i0[r2] * D + gk);
                        q1 = (const float4*)(P0 + (size_t)s_i1[r2] * D + gk);
                    } else if (gk < 256) {
                        q0 = (const float4*)(P1 + (size_t)grow * D + (gk - 128));
                    } else {
                        q0 = (const float4*)(P2 + (size_t)s_i2[r2] * D + (gk - 256));
                    }
                } else if (MODE == 1) {
                    if (gk < 128)      q0 = (const float4*)(P0 + (size_t)grow * D + gk);
                    else if (gk < 256) q0 = (const float4*)(P1 + (size_t)grow * D + (gk - 128));
                    else               q0 = (const float4*)(P2 + (size_t)s_i2[r2] * D + (gk - 256));
                } else {
                    if (gk < 128)      q0 = (const float4*)(P0 + (size_t)grow * D + gk);
                    else if (gk < 256) q0 = (const float4*)(P1 + (size_t)grow * D + (gk - 128));
                    else               q0 = (const float4*)(P2 + (size_t)grow * D + (gk - 256));
                }
#pragma unroll
                for (int q = 0; q < 4; q++) {
                    float4 a = q0[q];
                    if (MODE == 0 && q1) {
                        float4 b = q1[q];
                        a.x += b.x; a.y += b.y; a.z += b.z; a.w += b.w;
                    }
                    v[q * 4 + 0] = a.x; v[q * 4 + 1] = a.y;
                    v[q * 4 + 2] = a.z; v[q * 4 + 3] = a.w;
                }
            } else {
#pragma unroll
                for (int m = 0; m < 16; m++) v[m] = 0.f;
            }
            unsigned short t16[16];
#pragma unroll
            for (int m = 0; m < 16; m++) t16[m] = f2bf(v[m]);
            uint4* dp = (uint4*)&As[r2][khalf];
            dp[0] = *(const uint4*)&t16[0];
            dp[1] = *(const uint4*)&t16[8];
        }
        // ---- stage B: W1T bf16, 32B contiguous ----
        {
            const uint4* gp = (const uint4*)(W1T + (size_t)(colblk + r2) * KTOT + kt + khalf);
            uint4* dp = (uint4*)&Bs[r2][khalf];
            dp[0] = gp[0];
            dp[1] = gp[1];
        }
        __syncthreads();

        short8 af[4], bfr[4];
#pragma unroll
        for (int i = 0; i < 4; i++) af[i]  = *(const short8*)&As[wm * 64 + i * 16 + txl][kofs];
#pragma unroll
        for (int j = 0; j < 4; j++) bfr[j] = *(const short8*)&Bs[wn * 64 + j * 16 + txl][kofs];
#pragma unroll
        for (int i = 0; i < 4; i++)
#pragma unroll
            for (int j = 0; j < 4; j++)
                acc[i][j] = __builtin_amdgcn_mfma_f32_16x16x32_bf16(af[i], bfr[j], acc[i][j], 0, 0, 0);
        __syncthreads();
    }

    // ---- epilogue: +b1, bf16 into Zs, column stats ----
    float bias[4];
#pragma unroll
    for (int j = 0; j < 4; j++) bias[j] = b1[colblk + wn * 64 + j * 16 + txl];
    float csum[4] = {0.f, 0.f, 0.f, 0.f}, csq[4] = {0.f, 0.f, 0.f, 0.f};
#pragma unroll
    for (int i = 0; i < 4; i++) {
        int rl = wm * 64 + i * 16 + quad * 4;
#pragma unroll
        for (int j = 0; j < 4; j++) {
            int cl = wn * 64 + j * 16 + txl;
            floatx4 a = acc[i][j];
#pragma unroll
            for (int reg = 0; reg < 4; reg++) {
                float zv = a[reg] + bias[j];
                Zs[rl + reg][cl] = (short)f2bf(zv);
                if (row0 + rl + reg < M) { csum[j] += zv; csq[j] += zv * zv; }
            }
        }
    }
#pragma unroll
    for (int j = 0; j < 4; j++) {
        atomicAdd(&s_sum[wn * 64 + j * 16 + txl], csum[j]);
        atomicAdd(&s_sq[wn * 64 + j * 16 + txl], csq[j]);
    }
    __syncthreads();

    // coalesced copy Zs -> z
    {
        int grow = row0 + r2;
        if (grow < M) {
            const short* srcp = &Zs[r2][(tid & 1) * 64];
            unsigned short* dstp = z + (size_t)grow * KTOT + colblk + (tid & 1) * 64;
#pragma unroll
            for (int q = 0; q < 8; q++) {
                *(uint4*)(dstp + q * 8) = *(const uint4*)(srcp + q * 8);
            }
        }
    }
    if (tid < 128) {
        atomicAdd(&stat_sum[colblk + tid], s_sum[tid]);
        atomicAdd(&stat_sq[colblk + tid], s_sq[tid]);
    }
}

// ---------------------------------------------------------------------------
// BN finalize
// ---------------------------------------------------------------------------
__global__ void bn_finalize_kernel(const float* __restrict__ ssum,
                                   const float* __restrict__ ssq,
                                   const float* __restrict__ g1,
                                   const float* __restrict__ beta1,
                                   float invM,
                                   float* __restrict__ scale,
                                   float* __restrict__ shift)
{
    int j = threadIdx.x;
    if (j < KTOT) {
        float mu = ssum[j] * invM;
        float var = ssq[j] * invM - mu * mu;
        float sc = g1[j] * rsqrtf(var + BN_EPS);
        scale[j] = sc;
        shift[j] = beta1[j] - mu * sc;
    }
}

// ---------------------------------------------------------------------------
// GEMM2 (MFMA bf16): out = relu(z*scale+shift) @ W2 + b2. Plain stores only —
// all scatter-reductions are now done by gather/segmented-sum passes.
// ---------------------------------------------------------------------------
__global__ __launch_bounds__(256)
void gemm2_mfma_kernel(const unsigned short* __restrict__ z,  // [M][384] bf16
                       const float* __restrict__ scale,
                       const float* __restrict__ shift,
                       const unsigned short* __restrict__ W2T, // [N=128][K=384] bf16
                       const float* __restrict__ b2,
                       float* __restrict__ out,
                       int M)
{
    __shared__ __align__(16) short As[128][40];
    __shared__ __align__(16) short Bs[128][40];
    __shared__ float s_scale[KTOT], s_shift[KTOT];

    const int tid = threadIdx.x;
    const int row0 = blockIdx.x * 128;

    for (int i = tid; i < KTOT; i += 256) { s_scale[i] = scale[i]; s_shift[i] = shift[i]; }
    __syncthreads();

    const int lane = tid & 63;
    const int wave = tid >> 6;
    const int wm = wave >> 1, wn = wave & 1;
    const int txl = lane & 15;
    const int quad = lane >> 4;
    const int kofs = quad * 8;

    const int r2 = tid >> 1;
    const int khalf = (tid & 1) * 16;

    floatx4 acc[4][4] = {};

    for (int kt = 0; kt < KTOT; kt += 32) {
        // ---- stage A: z bf16 -> BN+ReLU -> bf16 LDS ----
        {
            int gk = kt + khalf;
            int grow = row0 + r2;
            unsigned short t16[16];
            if (grow < M) {
                const uint4* gp = (const uint4*)(z + (size_t)grow * KTOT + gk);
                uint4 w0 = gp[0], w1 = gp[1];
                const unsigned short* us = (const unsigned short*)&w0;
#pragma unroll
                for (int m = 0; m < 8; m++) {
                    float f = bf2f(us[m]);
                    f = fmaxf(f * s_scale[gk + m] + s_shift[gk + m], 0.f);
                    t16[m] = f2bf(f);
                }
                const unsigned short* us1 = (const unsigned short*)&w1;
#pragma unroll
                for (int m = 0; m < 8; m++) {
                    float f = bf2f(us1[m]);
                    f = fmaxf(f * s_scale[gk + 8 + m] + s_shift[gk + 8 + m], 0.f);
                    t16[8 + m] = f2bf(f);
                }
            } else {
#pragma unroll
                for (int m = 0; m < 16; m++) t16[m] = 0;
            }
            uint4* dp = (uint4*)&As[r2][khalf];
            dp[0] = *(const uint4*)&t16[0];
            dp[1] = *(const uint4*)&t16[8];
        }
        // ---- stage B ----
        {
            const uint4* gp = (const uint4*)(W2T + (size_t)r2 * KTOT + kt + khalf);
            uint4* dp = (uint4*)&Bs[r2][khalf];
            dp[0] = gp[0];
            dp[1] = gp[1];
        }
        __syncthreads();

        short8 af[4], bfr[4];
#pragma unroll
        for (int i = 0; i < 4; i++) af[i]  = *(const short8*)&As[wm * 64 + i * 16 + txl][kofs];
#pragma unroll
        for (int j = 0; j < 4; j++) bfr[j] = *(const short8*)&Bs[wn * 64 + j * 16 + txl][kofs];
#pragma unroll
        for (int i = 0; i < 4; i++)
#pragma unroll
            for (int j = 0; j < 4; j++)
                acc[i][j] = __builtin_amdgcn_mfma_f32_16x16x32_bf16(af[i], bfr[j], acc[i][j], 0, 0, 0);
        __syncthreads();
    }

    float bias[4];
#pragma unroll
    for (int j = 0; j < 4; j++) bias[j] = b2[wn * 64 + j * 16 + txl];
#pragma unroll
    for (int i = 0; i < 4; i++) {
#pragma unroll
        for (int reg = 0; reg < 4; reg++) {
            int rl = wm * 64 + i * 16 + quad * 4 + reg;
            int grow = row0 + rl;
            if (grow < M) {
#pragma unroll
                for (int j = 0; j < 4; j++) {
                    int c = wn * 64 + j * 16 + txl;
                    out[(size_t)grow * D + c] = acc[i][j][reg] + bias[j];
                }
            }
        }
    }
}

// ---------------------------------------------------------------------------
extern "C" void kernel_launch(void* const* d_in, const int* in_sizes, int n_in,
                              void* d_out, int out_size, void* d_ws, size_t ws_size,
                              hipStream_t stream)
{
    const float* h  = (const float*)d_in[0];
    const float* e  = (const float*)d_in[1];
    const float* u  = (const float*)d_in[2];
    const int* src  = (const int*)d_in[3];
    const int* dst  = (const int*)d_in[4];
    const int* gid  = (const int*)d_in[5];

    const float* bW1 = (const float*)d_in[6];  const float* bb1 = (const float*)d_in[7];
    const float* bg1 = (const float*)d_in[8];  const float* bbe = (const float*)d_in[9];
    const float* bW2 = (const float*)d_in[10]; const float* bb2 = (const float*)d_in[11];
    const float* aW1 = (const float*)d_in[12]; const float* ab1 = (const float*)d_in[13];
    const float* ag1 = (const float*)d_in[14]; const float* abe = (const float*)d_in[15];
    const float* aW2 = (const float*)d_in[16]; const float* ab2 = (const float*)d_in[17];
    const float* gW1 = (const float*)d_in[18]; const float* gb1 = (const float*)d_in[19];
    const float* gg1 = (const float*)d_in[20]; const float* gbe = (const float*)d_in[21];
    const float* gW2 = (const float*)d_in[22]; const float* gb2 = (const float*)d_in[23];

    const int N = in_sizes[0] / D;
    const int E = in_sizes[1] / D;
    const int G = in_sizes[2] / D;

    float* out   = (float*)d_out;
    float* h_new = out;
    float* e_new = out + (size_t)N * D;
    float* u_new = out + (size_t)N * D + (size_t)E * D;

    // workspace carve-up
    char* ws = (char*)d_ws;
    unsigned short* z = (unsigned short*)ws;
    size_t off = ((size_t)E * KTOT * sizeof(unsigned short) + 255) & ~(size_t)255;
    float* sum_e  = (float*)(ws + off); off += ((size_t)N * D * 4 + 255) & ~(size_t)255;
    float* sum_h  = (float*)(ws + off); off += ((size_t)N * D * 4 + 255) & ~(size_t)255;
    float* sum_hg = (float*)(ws + off); off += ((size_t)G * D * 4 + 255) & ~(size_t)255;
    float* sum_eg = (float*)(ws + off); off += ((size_t)G * D * 4 + 255) & ~(size_t)255;
    float* st_sum = (float*)(ws + off); off += KTOT * 4;
    float* st_sq  = (float*)(ws + off); off += KTOT * 4;
    float* bn_sc  = (float*)(ws + off); off += KTOT * 4;
    float* bn_sh  = (float*)(ws + off); off += KTOT * 4;
    off = (off + 255) & ~(size_t)255;
    unsigned short* w1t_b = (unsigned short*)(ws + off); off += (size_t)KTOT * KTOT * 2;
    unsigned short* w2t_b = (unsigned short*)(ws + off); off += (size_t)KTOT * D * 2;
    unsigned short* w1t_a = (unsigned short*)(ws + off); off += (size_t)KTOT * KTOT * 2;
    unsigned short* w2t_a = (unsigned short*)(ws + off); off += (size_t)KTOT * D * 2;
    unsigned short* w1t_g = (unsigned short*)(ws + off); off += (size_t)KTOT * KTOT * 2;
    unsigned short* w2t_g = (unsigned short*)(ws + off); off += (size_t)KTOT * D * 2;
    off = (off + 255) & ~(size_t)255;
    int* deg     = (int*)(ws + off); off += ((size_t)N * 4 + 255) & ~(size_t)255;
    int* offs    = (int*)(ws + off); off += ((size_t)N * 4 + 255) & ~(size_t)255;
    int* cursor  = (int*)(ws + off); off += ((size_t)N * 4 + 255) & ~(size_t)255;
    int* bsum    = (int*)(ws + off); off += ((size_t)1024 * 4 + 255) & ~(size_t)255;
    int* el_src  = (int*)(ws + off); off += ((size_t)E * 4 + 255) & ~(size_t)255;
    int* el_e    = (int*)(ws + off); off += ((size_t)E * 4 + 255) & ~(size_t)255;

    const dim3 blk(256);
    const int NB = (N + 255) / 256;   // scan blocks (391 for N=100000, fits 512-wide scan)

    // weight pre-pass (bf16 transpose)
    {
        int n1 = KTOT * KTOT, n2 = KTOT * D;
        convert_transpose_kernel<<<(n1 + 255) / 256, blk, 0, stream>>>(bW1, w1t_b, KTOT, KTOT);
        convert_transpose_kernel<<<(n2 + 255) / 256, blk, 0, stream>>>(bW2, w2t_b, KTOT, D);
        convert_transpose_kernel<<<(n1 + 255) / 256, blk, 0, stream>>>(aW1, w1t_a, KTOT, KTOT);
        convert_transpose_kernel<<<(n2 + 255) / 256, blk, 0, stream>>>(aW2, w2t_a, KTOT, D);
        convert_transpose_kernel<<<(n1 + 255) / 256, blk, 0, stream>>>(gW1, w1t_g, KTOT, KTOT);
        convert_transpose_kernel<<<(n2 + 255) / 256, blk, 0, stream>>>(gW2, w2t_g, KTOT, D);
    }

    // ---- CSR by dst ----
    hipMemsetAsync(deg, 0, (size_t)N * 4, stream);
    hist_kernel<<<(E + 255) / 256, blk, 0, stream>>>(dst, deg, E);
    scan_block_kernel<<<NB, blk, 0, stream>>>(deg, offs, bsum, N);
    scan_bsum_kernel<<<1, 512, 0, stream>>>(bsum, NB);
    scan_add_cursor_kernel<<<NB, blk, 0, stream>>>(offs, bsum, cursor, N);
    fill_kernel<<<(E + 255) / 256, blk, 0, stream>>>(src, dst, cursor, el_src, el_e, E);

    // ---- sum_h = h + gather(h[src] over CSR(dst)) ----
    gather_sum_h_kernel<<<(N * 32 + 255) / 256, blk, 0, stream>>>(h, offs, el_src, sum_h, N, E);

    // ---- edge MLP ----
    hipMemsetAsync(st_sum, 0, KTOT * 4, stream);
    hipMemsetAsync(st_sq,  0, KTOT * 4, stream);
    gemm1_mfma_kernel<0><<<dim3((E + 127) / 128, 3), blk, 0, stream>>>(
        h, e, u, src, dst, gid, w1t_b, bb1, z, st_sum, st_sq, E);
    bn_finalize_kernel<<<1, KTOT, 0, stream>>>(st_sum, st_sq, bg1, bbe, 1.0f / (float)E, bn_sc, bn_sh);
    gemm2_mfma_kernel<<<dim3((E + 127) / 128, 1), blk, 0, stream>>>(
        z, bn_sc, bn_sh, w2t_b, bb2, e_new, E);

    // ---- sum_e = gather(e_new over CSR(dst)) ----
    gather_sum_e_kernel<<<(N * 32 + 255) / 256, blk, 0, stream>>>(e_new, offs, el_e, sum_e, N, E);

    // ---- atom MLP ----
    hipMemsetAsync(st_sum, 0, KTOT * 4, stream);
    hipMemsetAsync(st_sq,  0, KTOT * 4, stream);
    gemm1_mfma_kernel<1><<<dim3((N + 127) / 128, 3), blk, 0, stream>>>(
        sum_h, sum_e, u, src, dst, gid, w1t_a, ab1, z, st_sum, st_sq, N);
    bn_finalize_kernel<<<1, KTOT, 0, stream>>>(st_sum, st_sq, ag1, abe, 1.0f / (float)N, bn_sc, bn_sh);
    gemm2_mfma_kernel<<<dim3((N + 127) / 128, 1), blk, 0, stream>>>(
        z, bn_sc, bn_sh, w2t_a, ab2, h_new, N);

    // ---- per-graph segmented sums (graph_id sorted -> no atomics) ----
    graph_seg_sum_kernel<<<G, 128, 0, stream>>>(h_new, sum_e, gid, sum_hg, sum_eg, N);

    // ---- global MLP ----
    hipMemsetAsync(st_sum, 0, KTOT * 4, stream);
    hipMemsetAsync(st_sq,  0, KTOT * 4, stream);
    gemm1_mfma_kernel<2><<<dim3((G + 127) / 128, 3), blk, 0, stream>>>(
        sum_hg, sum_eg, u, src, dst, gid, w1t_g, gb1, z, st_sum, st_sq, G);
    bn_finalize_kernel<<<1, KTOT, 0, stream>>>(st_sum, st_sq, gg1, gbe, 1.0f / (float)G, bn_sc, bn_sh);
    gemm2_mfma_kernel<<<dim3((G + 127) / 128, 1), blk, 0, stream>>>(
        z, bn_sc, bn_sh, w2t_g, gb2, u_new, G);
}